// Round 6
// baseline (193.945 us; speedup 1.0000x reference)
//
#include <hip/hip_runtime.h>

typedef __attribute__((ext_vector_type(8))) short bf16x8;
typedef __attribute__((ext_vector_type(4))) float f32x4;

// ---------------------------------------------------------------------------
// Posit(8,1) round-to-nearest quantization, bit-exact vs the jnp reference.
// two_es=2, npat=6, maxpos=2^12, minpos=2^-12. Result has <=4 fraction bits ->
// exactly representable in bf16 (and fp32).
// ---------------------------------------------------------------------------
__device__ __forceinline__ float posit_q(float x) {
  float ax = fabsf(x);
  ax = fmaxf(ax, 0x1p-12f);
  ax = fminf(ax, 0x1p12f);
  int s = (int)(__float_as_uint(ax) >> 23) - 127;   // floor(log2(ax)), exact
  int k = s >> 1;                                   // floor(s/2)
  int rlen = (k >= 0) ? (k + 2) : (1 - k);
  int fbits = 6 - rlen;
  fbits = fbits < 0 ? 0 : fbits;
  float m = ax * __uint_as_float((unsigned)(127 - s) << 23);  // [1,2)
  float fs = (float)(1 << fbits);
  float inv_fs = __uint_as_float((unsigned)(127 - fbits) << 23);
  float mq = rintf(m * fs) * inv_fs;                // round-half-even = jnp.round
  if (mq >= 2.0f) { s += 1; mq = 1.0f; }            // mantissa carry
  float y = mq * __uint_as_float((unsigned)(127 + s) << 23);
  y = fminf(y, 0x1p12f);
  y = copysignf(y, x);
  return (x == 0.0f) ? 0.0f : y;
}

__device__ __forceinline__ ushort4 quant4_bf16(float4 v) {
  ushort4 o;
  o.x = (ushort)(__float_as_uint(posit_q(v.x)) >> 16);
  o.y = (ushort)(__float_as_uint(posit_q(v.y)) >> 16);
  o.z = (ushort)(__float_as_uint(posit_q(v.z)) >> 16);
  o.w = (ushort)(__float_as_uint(posit_q(v.w)) >> 16);
  return o;
}

// One merged quantize kernel: x -> bf16, w -> bf16, bias -> fp32.
__global__ void posit_quant_all(const float* __restrict__ x,
                                const float* __restrict__ w,
                                const float* __restrict__ b,
                                ushort* __restrict__ Xq,
                                ushort* __restrict__ Wq,
                                float* __restrict__ bq,
                                int nx4, int nw4, int nb4) {
  int i = blockIdx.x * blockDim.x + threadIdx.x;
  if (i < nx4) {
    ((ushort4*)Xq)[i] = quant4_bf16(((const float4*)x)[i]);
  } else if (i < nx4 + nw4) {
    int j = i - nx4;
    ((ushort4*)Wq)[j] = quant4_bf16(((const float4*)w)[j]);
  } else if (i < nx4 + nw4 + nb4) {
    int j = i - nx4 - nw4;
    float4 v = ((const float4*)b)[j];
    float4 o;
    o.x = posit_q(v.x); o.y = posit_q(v.y);
    o.z = posit_q(v.z); o.w = posit_q(v.w);
    ((float4*)bq)[j] = o;
  }
}

// ---------------------------------------------------------------------------
// bf16 NT GEMM (A: MxK row-major, B: NxK row-major), C = A*B^T + bias.
// R6: register-prefetch K-loop (hipBLASLt/AITER dataflow). 256x128 tile,
// 512 threads (8 waves, 4x2), BK=64, single LDS buffer.
//   loop: global_load tile k+1 -> VGPRs   (no LDS dependence)
//         compute tile k (32 MFMA + 12 ds_read_b128)  <- covers load latency
//         barrier            (vmcnt drain already covered by compute)
//         ds_write regs -> LDS
//         barrier            (cheap lgkm drain)
// vs R5 where global_load_lds was immediately followed by the barrier (zero
// same-wave latency cover). R4's lesson: two EXPENSIVE drains lose; here both
// drains are cheap.
//
// Swizzle (verified 0 conflicts R3/R5): 16B k-chunk at position p of row r
// stored at p ^ (r&7). LDS element addresses identical to R5's
// global_load_lds layout -> fragment read indexing unchanged. ds_write_b128
// is lane-contiguous (1024 B per 64 lanes) -> conflict-free.
// ---------------------------------------------------------------------------
__global__ __launch_bounds__(512, 4) void posit_gemm(
    const ushort* __restrict__ A, const ushort* __restrict__ B,
    const float* __restrict__ bq, float* __restrict__ C,
    int M, int N, int K) {
  __shared__ ushort sA[256 * 64];   // 32 KB, row-major [256][64], chunk-swizzled
  __shared__ ushort sB[128 * 64];   // 16 KB

  const int tid = threadIdx.x;
  const int wave = tid >> 6;        // 0..7
  const int lane = tid & 63;
  const int wm = wave >> 1;         // 4x2 wave grid: wm 0..3, wn 0..1
  const int wn = wave & 1;
  const int m0 = blockIdx.y << 8;   // 256-row tiles
  const int n0 = blockIdx.x << 7;   // 128-col tiles

  // --- staging map (identical addresses to R5): round r covers 64 rows;
  // row = 64r + (wave<<3) + (lane>>3); swizzled k-chunk pos = lane&7.
  const int g8 = lane >> 3;                       // 0..7 == row&7
  const int qe = ((lane & 7) ^ g8) << 3;          // swizzled k-elem offset [0,64)
  const int rb = (wave << 3) + g8;                // row within 64-row round

  const ushort* Ag = A + (size_t)(m0 + rb) * K + qe;
  const ushort* Bg = B + (size_t)(n0 + rb) * K + qe;
  const size_t rstep = (size_t)64 * K;            // 64 rows per round

  // LDS element offset this lane writes: (r<<12) + (wave<<9) + (lane<<3)
  ushort* la = sA + (wave << 9) + (lane << 3);
  ushort* lb = sB + (wave << 9) + (lane << 3);

  // --- fragment reads: row = w?*64 + i*16 + fr; k-chunk p = kk*4 + t4,
  // stored at p ^ (fr&7).
  const int fr = lane & 15;
  const int t4 = lane >> 4;                       // 0..3
  const int pk0 = ((t4 ^ (fr & 7)) << 3);
  const int pk1 = (((4 + t4) ^ (fr & 7)) << 3);

  f32x4 acc[4][4];
#pragma unroll
  for (int i = 0; i < 4; i++)
#pragma unroll
    for (int j = 0; j < 4; j++) acc[i][j] = (f32x4){0.f, 0.f, 0.f, 0.f};

  bf16x8 pfA[4], pfB[2];

  auto loadregs = [&](int k0) {
#pragma unroll
    for (int r = 0; r < 4; r++)
      pfA[r] = *(const bf16x8*)(Ag + k0 + r * rstep);
#pragma unroll
    for (int r = 0; r < 2; r++)
      pfB[r] = *(const bf16x8*)(Bg + k0 + r * rstep);
  };

  auto writeregs = [&]() {
#pragma unroll
    for (int r = 0; r < 4; r++)
      *(bf16x8*)(la + (r << 12)) = pfA[r];
#pragma unroll
    for (int r = 0; r < 2; r++)
      *(bf16x8*)(lb + (r << 12)) = pfB[r];
  };

  // Prologue: tile 0 through regs into LDS.
  loadregs(0);
  writeregs();
  __syncthreads();

  for (int k0 = 0; k0 < K; k0 += 64) {
    const bool more = (k0 + 64) < K;
    if (more) loadregs(k0 + 64);     // issue early; consumed only after barrier

    // compute tile k0 (MFMAs independent of the in-flight loads)
#pragma unroll
    for (int kk = 0; kk < 2; kk++) {
      const int pk = kk ? pk1 : pk0;
      bf16x8 fa[4], fb[4];
#pragma unroll
      for (int i = 0; i < 4; i++)
        fa[i] = *(const bf16x8*)(sA + (((wm << 6) + (i << 4) + fr) << 6) + pk);
#pragma unroll
      for (int j = 0; j < 4; j++)
        fb[j] = *(const bf16x8*)(sB + (((wn << 6) + (j << 4) + fr) << 6) + pk);

#pragma unroll
      for (int i = 0; i < 4; i++)
#pragma unroll
        for (int j = 0; j < 4; j++)
          acc[i][j] = __builtin_amdgcn_mfma_f32_16x16x32_bf16(
              fa[i], fb[j], acc[i][j], 0, 0, 0);
    }
    __syncthreads();                 // all waves done reading tile k0
    if (more) {
      writeregs();                   // vmcnt drain here — covered by compute
      __syncthreads();               // writes visible (cheap lgkm drain)
    }
  }

  // Epilogue: C/D layout col = lane&15, row = (lane>>4)*4 + reg. Fuse bias.
  const int row0 = m0 + (wm << 6) + (t4 << 2);
  const int col0 = n0 + (wn << 6) + fr;
#pragma unroll
  for (int j = 0; j < 4; j++) {
    const int col = col0 + (j << 4);
    const float bv = bq[col];
#pragma unroll
    for (int i = 0; i < 4; i++) {
      const int row = row0 + (i << 4);
#pragma unroll
      for (int r = 0; r < 4; r++)
        C[(size_t)(row + r) * N + col] = acc[i][j][r] + bv;
    }
  }
}

extern "C" void kernel_launch(void* const* d_in, const int* in_sizes, int n_in,
                              void* d_out, int out_size, void* d_ws, size_t ws_size,
                              hipStream_t stream) {
  const float* x = (const float*)d_in[0];
  const float* w = (const float*)d_in[1];
  const float* bias = (const float*)d_in[2];
  float* out = (float*)d_out;

  const int out_f = in_sizes[2];                 // 2048
  const int in_f = in_sizes[1] / out_f;          // 2048
  const int m = in_sizes[0] / in_f;              // 8192
  const int k = in_f;

  // workspace layout: Xq bf16 | Wq bf16 | bq fp32
  ushort* Xq = (ushort*)d_ws;
  ushort* Wq = Xq + (size_t)m * k;
  float* bquant = (float*)(Wq + (size_t)out_f * k);

  const int nx4 = in_sizes[0] / 4;
  const int nw4 = in_sizes[1] / 4;
  const int nb4 = in_sizes[2] / 4;
  const int total4 = nx4 + nw4 + nb4;
  posit_quant_all<<<(total4 + 255) / 256, 256, 0, stream>>>(
      x, w, bias, Xq, Wq, bquant, nx4, nw4, nb4);

  dim3 grid(out_f / 128, m / 256);
  posit_gemm<<<grid, 512, 0, stream>>>(Xq, Wq, bquant, out, m, out_f, k);
}